// Round 1
// baseline (2140.986 us; speedup 1.0000x reference)
//
#include <hip/hip_runtime.h>
#include <math.h>

#define RNUM 14
#define NNODE 100000
#define ENUM 1600000
#define NBINS (RNUM * NNODE)
#define TILE 2048
#define NB1 ((NBINS + TILE - 1) / TILE)   // 684
#define NBLK ((NNODE + 63) / 64)          // 1563

// ---------------- counting sort: histogram ----------------
__global__ void hist_k(const int* __restrict__ dst, const int* __restrict__ et,
                       int* __restrict__ counts) {
    int e = blockIdx.x * 256 + threadIdx.x;
    if (e >= ENUM) return;
    atomicAdd(&counts[et[e] * NNODE + dst[e]], 1);
}

// ---------------- hierarchical exclusive scan ----------------
__global__ void scan_blocks_k(const int* __restrict__ counts, int* __restrict__ offs,
                              int* __restrict__ partials) {
    __shared__ int tsum[256];
    int blk = blockIdx.x, t = threadIdx.x;
    int base = blk * TILE + t * 8;
    int v[8];
    int s = 0;
#pragma unroll
    for (int j = 0; j < 8; j++) {
        int idx = base + j;
        v[j] = (idx < NBINS) ? counts[idx] : 0;
        s += v[j];
    }
    tsum[t] = s;
    __syncthreads();
#pragma unroll
    for (int off = 1; off < 256; off <<= 1) {
        int val = (t >= off) ? tsum[t - off] : 0;
        __syncthreads();
        if (t >= off) tsum[t] += val;
        __syncthreads();
    }
    int run = tsum[t] - s;  // exclusive prefix for this thread
#pragma unroll
    for (int j = 0; j < 8; j++) {
        int idx = base + j;
        if (idx < NBINS) offs[idx] = run;
        run += v[j];
    }
    if (t == 255) partials[blk] = tsum[255];
}

__global__ void scan_partials_k(int* partials) {
    __shared__ int sh[1024];
    int t = threadIdx.x;
    sh[t] = (t < NB1) ? partials[t] : 0;
    __syncthreads();
    for (int off = 1; off < 1024; off <<= 1) {
        int v = (t >= off) ? sh[t - off] : 0;
        __syncthreads();
        sh[t] += v;
        __syncthreads();
    }
    if (t < NB1) partials[t] = (t == 0) ? 0 : sh[t - 1];
}

__global__ void scan_add_k(int* __restrict__ offs, const int* __restrict__ partials) {
    int blk = blockIdx.x, t = threadIdx.x;
    int add = partials[blk];
    int base = blk * TILE + t * 8;
#pragma unroll
    for (int j = 0; j < 8; j++) {
        int idx = base + j;
        if (idx < NBINS) offs[idx] += add;
    }
    if (blk == 0 && t == 0) offs[NBINS] = ENUM;
}

// ---------------- counting sort: scatter ----------------
__global__ void scatter_k(const int* __restrict__ src, const int* __restrict__ dst,
                          const int* __restrict__ et, int* __restrict__ cursor,
                          int* __restrict__ ssrc) {
    int e = blockIdx.x * 256 + threadIdx.x;
    if (e >= ENUM) return;
    int key = et[e] * NNODE + dst[e];
    int p = atomicAdd(&cursor[key], 1);
    ssrc[p] = src[e];
}

// ---------------- W2[r] = sum_b comp2[r,b] * bases2[b] ----------------
__global__ void w2pre_k(const float* __restrict__ comp2, const float* __restrict__ bases2,
                        float* __restrict__ W2) {
    int idx = blockIdx.x * 256 + threadIdx.x;
    if (idx >= RNUM * 4096) return;
    int r = idx >> 12, io = idx & 4095;
    float s = 0.f;
#pragma unroll
    for (int b = 0; b < 8; b++) s += comp2[r * 8 + b] * bases2[b * 4096 + io];
    W2[idx] = s;
}

// ---------------- layer 1 aggregation: block-diag transform + seg-max + rel-sum ----------------
__global__ void agg1_k(const float* __restrict__ x, const int* __restrict__ offs,
                       const int* __restrict__ ssrc, const float* __restrict__ w1,
                       float* __restrict__ agg) {
    __shared__ float w1l[512];  // layout [i][b][o] = i*64 + lane  (lane = b*8+o)
    int r = blockIdx.x / NBLK;
    int dst_base = (blockIdx.x % NBLK) * 64;
    int t = threadIdx.x;
    for (int idx = t; idx < 512; idx += 256) {
        int i = idx >> 6, rem = idx & 63, b = rem >> 3, o = rem & 7;
        w1l[idx] = w1[r * 512 + b * 64 + i * 8 + o];
    }
    __syncthreads();
    int wave = t >> 6, lane = t & 63, b = lane >> 3;
    for (int q = 0; q < 16; q++) {
        int dstn = dst_base + wave * 16 + q;
        if (dstn >= NNODE) break;
        int bin = r * NNODE + dstn;
        int e0 = offs[bin], e1 = offs[bin + 1];
        if (e0 >= e1) continue;
        float m = -INFINITY;
        for (int e = e0; e < e1; e++) {
            int s = ssrc[e];
            const float4* xr = (const float4*)(x + (size_t)s * 64 + b * 8);
            float4 a0 = xr[0], a1 = xr[1];
            float msg = a0.x * w1l[lane]       + a0.y * w1l[64 + lane]
                      + a0.z * w1l[128 + lane] + a0.w * w1l[192 + lane]
                      + a1.x * w1l[256 + lane] + a1.y * w1l[320 + lane]
                      + a1.z * w1l[384 + lane] + a1.w * w1l[448 + lane];
            m = fmaxf(m, msg);
        }
        atomicAdd(&agg[(size_t)dstn * 64 + lane], m);
    }
}

// ---------------- layer 2 aggregation: dense 64x64 transform + seg-max + rel-sum ----------------
__global__ void agg2_k(const float* __restrict__ x1, const int* __restrict__ offs,
                       const int* __restrict__ ssrc, const float* __restrict__ W2,
                       float* __restrict__ out) {
    __shared__ float w2l[4096];  // W2[r] row-major [i][o]
    int r = blockIdx.x / NBLK;
    int dst_base = (blockIdx.x % NBLK) * 64;
    int t = threadIdx.x;
    const float* w2r = W2 + r * 4096;
    for (int idx = t * 4; idx < 4096; idx += 1024)
        *(float4*)&w2l[idx] = *(const float4*)&w2r[idx];
    __syncthreads();
    int wave = t >> 6, lane = t & 63;
    for (int q = 0; q < 16; q++) {
        int dstn = dst_base + wave * 16 + q;
        if (dstn >= NNODE) break;
        int bin = r * NNODE + dstn;
        int e0 = offs[bin], e1 = offs[bin + 1];
        if (e0 >= e1) continue;
        float m = -INFINITY;
        for (int e = e0; e < e1; e++) {
            int s = ssrc[e];
            float xv = x1[(size_t)s * 64 + lane];
            float msg = 0.f;
#pragma unroll
            for (int i = 0; i < 64; i++) msg += __shfl(xv, i, 64) * w2l[i * 64 + lane];
            m = fmaxf(m, msg);
        }
        atomicAdd(&out[(size_t)dstn * 64 + lane], m);
    }
}

// ---------------- finalize: add root GEMM + bias (+relu) ----------------
__global__ void finalize1_k(const float* __restrict__ x, const float* __restrict__ root1,
                            const float* __restrict__ bias1, const float* __restrict__ agg,
                            float* __restrict__ x1) {
    __shared__ float rl[4096];
    __shared__ float bl[64];
    int t = threadIdx.x;
    for (int idx = t * 4; idx < 4096; idx += 1024)
        *(float4*)&rl[idx] = *(const float4*)&root1[idx];
    if (t < 64) bl[t] = bias1[t];
    __syncthreads();
    int wave = t >> 6, lane = t & 63;
    int n = blockIdx.x * 4 + wave;
    if (n >= NNODE) return;
    float xv = x[(size_t)n * 64 + lane];
    float acc = agg[(size_t)n * 64 + lane] + bl[lane];
#pragma unroll
    for (int i = 0; i < 64; i++) acc += __shfl(xv, i, 64) * rl[i * 64 + lane];
    x1[(size_t)n * 64 + lane] = fmaxf(acc, 0.f);
}

__global__ void finalize2_k(const float* __restrict__ x1, const float* __restrict__ root2,
                            const float* __restrict__ bias2, float* __restrict__ out) {
    __shared__ float rl[4096];
    __shared__ float bl[64];
    int t = threadIdx.x;
    for (int idx = t * 4; idx < 4096; idx += 1024)
        *(float4*)&rl[idx] = *(const float4*)&root2[idx];
    if (t < 64) bl[t] = bias2[t];
    __syncthreads();
    int wave = t >> 6, lane = t & 63;
    int n = blockIdx.x * 4 + wave;
    if (n >= NNODE) return;
    float xv = x1[(size_t)n * 64 + lane];
    float acc = out[(size_t)n * 64 + lane] + bl[lane];
#pragma unroll
    for (int i = 0; i < 64; i++) acc += __shfl(xv, i, 64) * rl[i * 64 + lane];
    out[(size_t)n * 64 + lane] = acc;
}

extern "C" void kernel_launch(void* const* d_in, const int* in_sizes, int n_in,
                              void* d_out, int out_size, void* d_ws, size_t ws_size,
                              hipStream_t stream) {
    const float* x      = (const float*)d_in[0];
    const int*   ei     = (const int*)d_in[1];
    const int*   et     = (const int*)d_in[2];
    const float* w1     = (const float*)d_in[3];
    const float* root1  = (const float*)d_in[4];
    const float* bias1  = (const float*)d_in[5];
    const float* comp2  = (const float*)d_in[6];
    const float* bases2 = (const float*)d_in[7];
    const float* root2  = (const float*)d_in[8];
    const float* bias2  = (const float*)d_in[9];
    const int* srcv = ei;
    const int* dstv = ei + ENUM;
    float* out = (float*)d_out;

    char* w = (char*)d_ws;
    size_t off = 0;
    auto alloc = [&](size_t bytes) -> void* {
        void* p = w + off;
        off += (bytes + 255) & ~(size_t)255;
        return p;
    };
    int*   offs     = (int*)alloc((NBINS + 1) * sizeof(int));
    int*   cursor   = (int*)alloc(NBINS * sizeof(int));
    int*   partials = (int*)alloc(1024 * sizeof(int));
    int*   ssrc     = (int*)alloc((size_t)ENUM * sizeof(int));
    float* agg1v    = (float*)alloc((size_t)NNODE * 64 * sizeof(float));
    float* x1       = (float*)alloc((size_t)NNODE * 64 * sizeof(float));
    float* W2       = (float*)alloc((size_t)RNUM * 4096 * sizeof(float));
    if (off > ws_size) return;  // workspace too small — fail visibly

    hipMemsetAsync(cursor, 0, NBINS * sizeof(int), stream);
    hipMemsetAsync(agg1v, 0, (size_t)NNODE * 64 * sizeof(float), stream);
    hipMemsetAsync(d_out, 0, (size_t)NNODE * 64 * sizeof(float), stream);

    hist_k<<<(ENUM + 255) / 256, 256, 0, stream>>>(dstv, et, cursor);
    scan_blocks_k<<<NB1, 256, 0, stream>>>(cursor, offs, partials);
    scan_partials_k<<<1, 1024, 0, stream>>>(partials);
    scan_add_k<<<NB1, 256, 0, stream>>>(offs, partials);
    hipMemcpyAsync(cursor, offs, NBINS * sizeof(int), hipMemcpyDeviceToDevice, stream);
    scatter_k<<<(ENUM + 255) / 256, 256, 0, stream>>>(srcv, dstv, et, cursor, ssrc);
    w2pre_k<<<(RNUM * 4096 + 255) / 256, 256, 0, stream>>>(comp2, bases2, W2);

    agg1_k<<<RNUM * NBLK, 256, 0, stream>>>(x, offs, ssrc, w1, agg1v);
    finalize1_k<<<(NNODE + 3) / 4, 256, 0, stream>>>(x, root1, bias1, agg1v, x1);
    agg2_k<<<RNUM * NBLK, 256, 0, stream>>>(x1, offs, ssrc, W2, out);
    finalize2_k<<<(NNODE + 3) / 4, 256, 0, stream>>>(x1, root2, bias2, out);
}

// Round 2
// 682.337 us; speedup vs baseline: 3.1377x; 3.1377x over previous
//
#include <hip/hip_runtime.h>
#include <math.h>

#define RNUM 14
#define NNODE 100000
#define ENUM 1600000
#define NBINS (RNUM * NNODE)
#define TILE 2048
#define NB1 ((NBINS + TILE - 1) / TILE)   // 684
#define NT16 (NNODE / 16)                 // 6250 16-node tiles (100000 % 16 == 0)
#define NTB ((NT16 + 15) / 16)            // 391 blocks of 256 nodes

typedef __attribute__((ext_vector_type(8))) short bf16x8;
typedef __attribute__((ext_vector_type(4))) float f32x4;

__device__ inline unsigned short f2bf(float f) {
    unsigned u = __builtin_bit_cast(unsigned, f);
    u += 0x7FFF + ((u >> 16) & 1);          // round-to-nearest-even
    return (unsigned short)(u >> 16);
}
__device__ inline float bf2f(unsigned short h) {
    unsigned u = ((unsigned)h) << 16;
    return __builtin_bit_cast(float, u);
}

// ---------------- counting sort ----------------
__global__ void hist_k(const int* __restrict__ dst, const int* __restrict__ et,
                       int* __restrict__ counts) {
    int e = blockIdx.x * 256 + threadIdx.x;
    if (e >= ENUM) return;
    atomicAdd(&counts[et[e] * NNODE + dst[e]], 1);
}

__global__ void scan_blocks_k(const int* __restrict__ counts, int* __restrict__ offs,
                              int* __restrict__ partials) {
    __shared__ int tsum[256];
    int blk = blockIdx.x, t = threadIdx.x;
    int base = blk * TILE + t * 8;
    int v[8];
    int s = 0;
#pragma unroll
    for (int j = 0; j < 8; j++) {
        int idx = base + j;
        v[j] = (idx < NBINS) ? counts[idx] : 0;
        s += v[j];
    }
    tsum[t] = s;
    __syncthreads();
#pragma unroll
    for (int off = 1; off < 256; off <<= 1) {
        int val = (t >= off) ? tsum[t - off] : 0;
        __syncthreads();
        if (t >= off) tsum[t] += val;
        __syncthreads();
    }
    int run = tsum[t] - s;
#pragma unroll
    for (int j = 0; j < 8; j++) {
        int idx = base + j;
        if (idx < NBINS) offs[idx] = run;
        run += v[j];
    }
    if (t == 255) partials[blk] = tsum[255];
}

__global__ void scan_partials_k(int* partials) {
    __shared__ int sh[1024];
    int t = threadIdx.x;
    sh[t] = (t < NB1) ? partials[t] : 0;
    __syncthreads();
    for (int off = 1; off < 1024; off <<= 1) {
        int v = (t >= off) ? sh[t - off] : 0;
        __syncthreads();
        sh[t] += v;
        __syncthreads();
    }
    if (t < NB1) partials[t] = (t == 0) ? 0 : sh[t - 1];
}

__global__ void scan_add_k(int* __restrict__ offs, const int* __restrict__ partials) {
    int blk = blockIdx.x, t = threadIdx.x;
    int add = partials[blk];
    int base = blk * TILE + t * 8;
#pragma unroll
    for (int j = 0; j < 8; j++) {
        int idx = base + j;
        if (idx < NBINS) offs[idx] += add;
    }
    if (blk == 0 && t == 0) offs[NBINS] = ENUM;
}

__global__ void scatter_k(const int* __restrict__ src, const int* __restrict__ dst,
                          const int* __restrict__ et, int* __restrict__ cursor,
                          int* __restrict__ ssrc) {
    int e = blockIdx.x * 256 + threadIdx.x;
    if (e >= ENUM) return;
    int key = et[e] * NNODE + dst[e];
    int p = atomicAdd(&cursor[key], 1);
    ssrc[p] = src[e];
}

// ---------------- weight pre-pack into MFMA B-fragment order ----------------
// F[r][kh][ot][lane][j] : idx = r*4096 + kh*2048 + ot*512 + lane*8 + j
// B-frag (16x16x32): lane holds B[k = kh*32 + (lane>>4)*8 + j][col = ot*16 + (lane&15)]

__global__ void wfrag1_k(const float* __restrict__ w1, unsigned short* __restrict__ F) {
    int idx = blockIdx.x * 256 + threadIdx.x;
    if (idx >= RNUM * 4096) return;
    int j = idx & 7, lane = (idx >> 3) & 63, ot = (idx >> 9) & 3, kh = (idx >> 11) & 1, r = idx >> 12;
    int k = kh * 32 + (lane >> 4) * 8 + j;
    int c = ot * 16 + (lane & 15);
    int bi = k >> 3, bo = c >> 3;
    float v = 0.f;
    if (bi == bo) v = w1[((r * 8 + bi) * 8 + (k & 7)) * 8 + (c & 7)];
    F[idx] = f2bf(v);
}

__global__ void wfrag2_k(const float* __restrict__ comp2, const float* __restrict__ bases2,
                         unsigned short* __restrict__ F) {
    int idx = blockIdx.x * 256 + threadIdx.x;
    if (idx >= RNUM * 4096) return;
    int j = idx & 7, lane = (idx >> 3) & 63, ot = (idx >> 9) & 3, kh = (idx >> 11) & 1, r = idx >> 12;
    int k = kh * 32 + (lane >> 4) * 8 + j;
    int c = ot * 16 + (lane & 15);
    float s = 0.f;
#pragma unroll
    for (int b = 0; b < 8; b++) s += comp2[r * 8 + b] * bases2[(b * 64 + k) * 64 + c];
    F[idx] = f2bf(s);
}

__global__ void rootfrag_k(const float* __restrict__ W, unsigned short* __restrict__ F) {
    int idx = blockIdx.x * 256 + threadIdx.x;
    if (idx >= 4096) return;
    int j = idx & 7, lane = (idx >> 3) & 63, ot = (idx >> 9) & 3, kh = (idx >> 11) & 1;
    int k = kh * 32 + (lane >> 4) * 8 + j;
    int c = ot * 16 + (lane & 15);
    F[idx] = f2bf(W[k * 64 + c]);
}

__global__ void xb_k(const float* __restrict__ x, unsigned short* __restrict__ xb) {
    int idx = blockIdx.x * 256 + threadIdx.x;
    if (idx >= NNODE * 64) return;
    xb[idx] = f2bf(x[idx]);
}

// ---------------- GEMM: Y[r][n][:] = A[n][:] @ W[r]  (bf16 in, bf16 out) ----------------
__global__ void __launch_bounds__(256) gemm_k(const unsigned short* __restrict__ A,
                                              const unsigned short* __restrict__ F,
                                              unsigned short* __restrict__ Y) {
    int tb = blockIdx.x % NTB;
    int r  = blockIdx.x / NTB;
    int wave = threadIdx.x >> 6, lane = threadIdx.x & 63;
    const unsigned short* Fr = F + (size_t)r * 4096;
    bf16x8 bf[2][4];
#pragma unroll
    for (int kh = 0; kh < 2; kh++)
#pragma unroll
        for (int ot = 0; ot < 4; ot++)
            bf[kh][ot] = *(const bf16x8*)(Fr + ((kh * 4 + ot) * 64 + lane) * 8);
    int arow = lane & 15;
    int acol = (lane >> 4) * 8;
    for (int s = 0; s < 4; s++) {
        int nt = tb * 16 + wave * 4 + s;
        if (nt >= NT16) break;
        int nbase = nt * 16;
        const unsigned short* Arow = A + (size_t)(nbase + arow) * 64;
        bf16x8 a0 = *(const bf16x8*)(Arow + acol);
        bf16x8 a1 = *(const bf16x8*)(Arow + 32 + acol);
        f32x4 acc[4];
#pragma unroll
        for (int ot = 0; ot < 4; ot++) {
            acc[ot] = (f32x4){0.f, 0.f, 0.f, 0.f};
            acc[ot] = __builtin_amdgcn_mfma_f32_16x16x32_bf16(a0, bf[0][ot], acc[ot], 0, 0, 0);
            acc[ot] = __builtin_amdgcn_mfma_f32_16x16x32_bf16(a1, bf[1][ot], acc[ot], 0, 0, 0);
        }
        // C layout: col = lane&15, row = (lane>>4)*4 + j  -> direct scattered bf16 stores
        unsigned short* Yr = Y + ((size_t)r * NNODE + nbase) * 64;
#pragma unroll
        for (int ot = 0; ot < 4; ot++)
#pragma unroll
            for (int j = 0; j < 4; j++)
                Yr[((lane >> 4) * 4 + j) * 64 + ot * 16 + (lane & 15)] = f2bf(acc[ot][j]);
    }
}

// ---------------- aggregation: one wave per dst node, loop relations ----------------
// flags: 1=first chunk, 2=last chunk, 4=layer1 (relu + bf16 out to x1b)
__global__ void __launch_bounds__(256) agg_k(
    const unsigned short* __restrict__ H, const int* __restrict__ offs,
    const int* __restrict__ ssrc, const unsigned short* __restrict__ xrootb,
    const float* __restrict__ bias, float* __restrict__ aggbuf,
    unsigned short* __restrict__ x1b, float* __restrict__ outf,
    int r0, int rcnt, int flags) {
    int d = blockIdx.x * 4 + (threadIdx.x >> 6);
    if (d >= NNODE) return;
    int lane = threadIdx.x & 63;
    float msum = 0.f;
    for (int rr = 0; rr < rcnt; rr++) {
        int bin = (r0 + rr) * NNODE + d;
        int e0 = offs[bin], e1 = offs[bin + 1];
        if (e0 >= e1) continue;
        const unsigned short* Hs = H + (size_t)rr * NNODE * 64;
        float m = -INFINITY;
        for (int e = e0; e < e1; e++) {
            int s = ssrc[e];
            m = fmaxf(m, bf2f(Hs[(size_t)s * 64 + lane]));
        }
        msum += m;
    }
    size_t o = (size_t)d * 64 + lane;
    if (!(flags & 1)) msum += aggbuf[o];
    if (!(flags & 2)) { aggbuf[o] = msum; return; }
    float v = msum + bf2f(xrootb[o]) + bias[lane];
    if (flags & 4) x1b[o] = f2bf(fmaxf(v, 0.f));
    else outf[o] = v;
}

extern "C" void kernel_launch(void* const* d_in, const int* in_sizes, int n_in,
                              void* d_out, int out_size, void* d_ws, size_t ws_size,
                              hipStream_t stream) {
    const float* x      = (const float*)d_in[0];
    const int*   ei     = (const int*)d_in[1];
    const int*   et     = (const int*)d_in[2];
    const float* w1     = (const float*)d_in[3];
    const float* root1  = (const float*)d_in[4];
    const float* bias1  = (const float*)d_in[5];
    const float* comp2  = (const float*)d_in[6];
    const float* bases2 = (const float*)d_in[7];
    const float* root2  = (const float*)d_in[8];
    const float* bias2  = (const float*)d_in[9];
    const int* srcv = ei;
    const int* dstv = ei + ENUM;
    float* out = (float*)d_out;

    char* w = (char*)d_ws;
    size_t off = 0;
    auto alloc = [&](size_t bytes) -> void* {
        void* p = w + off;
        off += (bytes + 255) & ~(size_t)255;
        return p;
    };
    int*   offs     = (int*)alloc((NBINS + 1) * sizeof(int));
    int*   cursor   = (int*)alloc(NBINS * sizeof(int));
    int*   partials = (int*)alloc(1024 * sizeof(int));
    int*   ssrc     = (int*)alloc((size_t)ENUM * sizeof(int));
    unsigned short* xb     = (unsigned short*)alloc((size_t)NNODE * 64 * 2); // also x1b
    unsigned short* xrootb = (unsigned short*)alloc((size_t)NNODE * 64 * 2);
    float*          aggbuf = (float*)alloc((size_t)NNODE * 64 * 4);
    unsigned short* frag1  = (unsigned short*)alloc((size_t)RNUM * 4096 * 2);
    unsigned short* frag2  = (unsigned short*)alloc((size_t)RNUM * 4096 * 2);
    unsigned short* rootf1 = (unsigned short*)alloc(4096 * 2);
    unsigned short* rootf2 = (unsigned short*)alloc(4096 * 2);
    size_t fixed = off;
    if (fixed > ws_size) return;  // workspace too small — fail visibly
    size_t slab = ((size_t)NNODE * 64 * 2 + 255) & ~(size_t)255;
    int r_per = (int)((ws_size - fixed) / slab);
    if (r_per < 1) return;        // fail visibly
    if (r_per > RNUM) r_per = RNUM;
    unsigned short* H = (unsigned short*)alloc((size_t)r_per * slab);

    hipMemsetAsync(cursor, 0, NBINS * sizeof(int), stream);

    hist_k<<<(ENUM + 255) / 256, 256, 0, stream>>>(dstv, et, cursor);
    scan_blocks_k<<<NB1, 256, 0, stream>>>(cursor, offs, partials);
    scan_partials_k<<<1, 1024, 0, stream>>>(partials);
    scan_add_k<<<NB1, 256, 0, stream>>>(offs, partials);
    hipMemcpyAsync(cursor, offs, NBINS * sizeof(int), hipMemcpyDeviceToDevice, stream);
    scatter_k<<<(ENUM + 255) / 256, 256, 0, stream>>>(srcv, dstv, et, cursor, ssrc);

    wfrag1_k<<<(RNUM * 4096 + 255) / 256, 256, 0, stream>>>(w1, frag1);
    wfrag2_k<<<(RNUM * 4096 + 255) / 256, 256, 0, stream>>>(comp2, bases2, frag2);
    rootfrag_k<<<16, 256, 0, stream>>>(root1, rootf1);
    rootfrag_k<<<16, 256, 0, stream>>>(root2, rootf2);
    xb_k<<<(NNODE * 64 + 255) / 256, 256, 0, stream>>>(x, xb);

    int nch = (RNUM + r_per - 1) / r_per;
    int aggGrid = (NNODE + 3) / 4;

    // ---- layer 1 ----
    gemm_k<<<NTB, 256, 0, stream>>>(xb, rootf1, xrootb);
    for (int c = 0; c < nch; c++) {
        int r0 = c * r_per;
        int rcnt = (RNUM - r0 < r_per) ? (RNUM - r0) : r_per;
        gemm_k<<<rcnt * NTB, 256, 0, stream>>>(xb, frag1 + (size_t)r0 * 4096, H);
        int flags = 4 | (c == 0 ? 1 : 0) | (c == nch - 1 ? 2 : 0);
        agg_k<<<aggGrid, 256, 0, stream>>>(H, offs, ssrc, xrootb, bias1, aggbuf,
                                           xb /* x1b overwrites xb */, out, r0, rcnt, flags);
    }

    // ---- layer 2 ----
    gemm_k<<<NTB, 256, 0, stream>>>(xb /* = x1b */, rootf2, xrootb);
    for (int c = 0; c < nch; c++) {
        int r0 = c * r_per;
        int rcnt = (RNUM - r0 < r_per) ? (RNUM - r0) : r_per;
        gemm_k<<<rcnt * NTB, 256, 0, stream>>>(xb, frag2 + (size_t)r0 * 4096, H);
        int flags = (c == 0 ? 1 : 0) | (c == nch - 1 ? 2 : 0);
        agg_k<<<aggGrid, 256, 0, stream>>>(H, offs, ssrc, xrootb, bias2, aggbuf,
                                           xb, out, r0, rcnt, flags);
    }
}

// Round 3
// 577.860 us; speedup vs baseline: 3.7050x; 1.1808x over previous
//
#include <hip/hip_runtime.h>
#include <math.h>

#define RNUM 14
#define NNODE 100000
#define ENUM 1600000
#define NBINS2 (NNODE * 16)               // transposed key: dst*16 + rel (rel<16)
#define TILE 2048
#define NBSC ((NBINS2 + TILE - 1) / TILE) // 782 scan blocks
#define NT16 (NNODE / 16)                 // 6250
#define NTB ((NT16 + 15) / 16)            // 391

typedef __attribute__((ext_vector_type(8))) short bf16x8;
typedef __attribute__((ext_vector_type(4))) float f32x4;

__device__ inline unsigned short f2bf(float f) {
    unsigned u = __builtin_bit_cast(unsigned, f);
    u += 0x7FFF + ((u >> 16) & 1);
    return (unsigned short)(u >> 16);
}
__device__ inline float bf2f(unsigned short h) {
    unsigned u = ((unsigned)h) << 16;
    return __builtin_bit_cast(float, u);
}
__device__ inline int uload(const int* __restrict__ p) {
    return __builtin_amdgcn_readfirstlane(*p);
}

// ---------------- counting sort (key = dst*16 + rel) ----------------
__global__ void hist_k(const int* __restrict__ dst, const int* __restrict__ et,
                       int* __restrict__ counts) {
    int e = blockIdx.x * 256 + threadIdx.x;
    if (e >= ENUM) return;
    atomicAdd(&counts[dst[e] * 16 + et[e]], 1);
}

__global__ void scan_blocks_k(const int* __restrict__ counts, int* __restrict__ offs,
                              int* __restrict__ partials) {
    __shared__ int tsum[256];
    int blk = blockIdx.x, t = threadIdx.x;
    int base = blk * TILE + t * 8;
    int v[8];
    int s = 0;
#pragma unroll
    for (int j = 0; j < 8; j++) {
        int idx = base + j;
        v[j] = (idx < NBINS2) ? counts[idx] : 0;
        s += v[j];
    }
    tsum[t] = s;
    __syncthreads();
#pragma unroll
    for (int off = 1; off < 256; off <<= 1) {
        int val = (t >= off) ? tsum[t - off] : 0;
        __syncthreads();
        if (t >= off) tsum[t] += val;
        __syncthreads();
    }
    int run = tsum[t] - s;
#pragma unroll
    for (int j = 0; j < 8; j++) {
        int idx = base + j;
        if (idx < NBINS2) offs[idx] = run;
        run += v[j];
    }
    if (t == 255) partials[blk] = tsum[255];
}

__global__ void scan_partials_k(int* partials) {
    __shared__ int sh[1024];
    int t = threadIdx.x;
    sh[t] = (t < NBSC) ? partials[t] : 0;
    __syncthreads();
    for (int off = 1; off < 1024; off <<= 1) {
        int v = (t >= off) ? sh[t - off] : 0;
        __syncthreads();
        sh[t] += v;
        __syncthreads();
    }
    if (t < NBSC) partials[t] = (t == 0) ? 0 : sh[t - 1];
}

__global__ void scan_add_k(int* __restrict__ offs, const int* __restrict__ partials) {
    int blk = blockIdx.x, t = threadIdx.x;
    int add = partials[blk];
    int base = blk * TILE + t * 8;
#pragma unroll
    for (int j = 0; j < 8; j++) {
        int idx = base + j;
        if (idx < NBINS2) offs[idx] += add;
    }
    if (blk == 0 && t == 0) offs[NBINS2] = ENUM;
}

__global__ void scatter_k(const int* __restrict__ src, const int* __restrict__ dst,
                          const int* __restrict__ et, int* __restrict__ cursor,
                          int* __restrict__ ssrc) {
    int e = blockIdx.x * 256 + threadIdx.x;
    if (e >= ENUM) return;
    int key = dst[e] * 16 + et[e];
    int p = atomicAdd(&cursor[key], 1);
    ssrc[p] = src[e];
}

// ---------------- weight pre-pack into MFMA B-fragment order ----------------
__global__ void wfrag1_k(const float* __restrict__ w1, unsigned short* __restrict__ F) {
    int idx = blockIdx.x * 256 + threadIdx.x;
    if (idx >= RNUM * 4096) return;
    int j = idx & 7, lane = (idx >> 3) & 63, ot = (idx >> 9) & 3, kh = (idx >> 11) & 1, r = idx >> 12;
    int k = kh * 32 + (lane >> 4) * 8 + j;
    int c = ot * 16 + (lane & 15);
    int bi = k >> 3, bo = c >> 3;
    float v = 0.f;
    if (bi == bo) v = w1[((r * 8 + bi) * 8 + (k & 7)) * 8 + (c & 7)];
    F[idx] = f2bf(v);
}

__global__ void wfrag2_k(const float* __restrict__ comp2, const float* __restrict__ bases2,
                         unsigned short* __restrict__ F) {
    int idx = blockIdx.x * 256 + threadIdx.x;
    if (idx >= RNUM * 4096) return;
    int j = idx & 7, lane = (idx >> 3) & 63, ot = (idx >> 9) & 3, kh = (idx >> 11) & 1, r = idx >> 12;
    int k = kh * 32 + (lane >> 4) * 8 + j;
    int c = ot * 16 + (lane & 15);
    float s = 0.f;
#pragma unroll
    for (int b = 0; b < 8; b++) s += comp2[r * 8 + b] * bases2[(b * 64 + k) * 64 + c];
    F[idx] = f2bf(s);
}

__global__ void rootfrag_k(const float* __restrict__ W, unsigned short* __restrict__ F) {
    int idx = blockIdx.x * 256 + threadIdx.x;
    if (idx >= 4096) return;
    int j = idx & 7, lane = (idx >> 3) & 63, ot = (idx >> 9) & 3, kh = (idx >> 11) & 1;
    int k = kh * 32 + (lane >> 4) * 8 + j;
    int c = ot * 16 + (lane & 15);
    F[idx] = f2bf(W[k * 64 + c]);
}

__global__ void xb_k(const float* __restrict__ x, unsigned short* __restrict__ xb) {
    int idx = blockIdx.x * 256 + threadIdx.x;
    if (idx >= NNODE * 64) return;
    xb[idx] = f2bf(x[idx]);
}

// ---------------- GEMM: Y[r][n][:] = A[n][:] @ W[r]  (bf16 in, bf16 out) ----------------
__global__ void __launch_bounds__(256) gemm_k(const unsigned short* __restrict__ A,
                                              const unsigned short* __restrict__ F,
                                              unsigned short* __restrict__ Y) {
    int tb = blockIdx.x % NTB;
    int r  = blockIdx.x / NTB;
    int wave = threadIdx.x >> 6, lane = threadIdx.x & 63;
    const unsigned short* Fr = F + (size_t)r * 4096;
    bf16x8 bf[2][4];
#pragma unroll
    for (int kh = 0; kh < 2; kh++)
#pragma unroll
        for (int ot = 0; ot < 4; ot++)
            bf[kh][ot] = *(const bf16x8*)(Fr + ((kh * 4 + ot) * 64 + lane) * 8);
    int arow = lane & 15;
    int acol = (lane >> 4) * 8;
    for (int s = 0; s < 4; s++) {
        int nt = tb * 16 + wave * 4 + s;
        if (nt >= NT16) break;
        int nbase = nt * 16;
        const unsigned short* Arow = A + (size_t)(nbase + arow) * 64;
        bf16x8 a0 = *(const bf16x8*)(Arow + acol);
        bf16x8 a1 = *(const bf16x8*)(Arow + 32 + acol);
        f32x4 acc[4];
#pragma unroll
        for (int ot = 0; ot < 4; ot++) {
            acc[ot] = (f32x4){0.f, 0.f, 0.f, 0.f};
            acc[ot] = __builtin_amdgcn_mfma_f32_16x16x32_bf16(a0, bf[0][ot], acc[ot], 0, 0, 0);
            acc[ot] = __builtin_amdgcn_mfma_f32_16x16x32_bf16(a1, bf[1][ot], acc[ot], 0, 0, 0);
        }
        unsigned short* Yr = Y + ((size_t)r * NNODE + nbase) * 64;
#pragma unroll
        for (int ot = 0; ot < 4; ot++)
#pragma unroll
            for (int j = 0; j < 4; j++)
                Yr[((lane >> 4) * 4 + j) * 64 + ot * 16 + (lane & 15)] = f2bf(acc[ot][j]);
    }
}

// ---------------- aggregation ----------------
__device__ inline float seg_max(const unsigned short* __restrict__ Hs,
                                const int* __restrict__ ssrc, int e, int ee, int lane) {
    float m = -INFINITY;
    for (; e + 4 <= ee; e += 4) {
        int s0 = uload(ssrc + e);
        int s1 = uload(ssrc + e + 1);
        int s2 = uload(ssrc + e + 2);
        int s3 = uload(ssrc + e + 3);
        float h0 = bf2f(Hs[(size_t)s0 * 64 + lane]);
        float h1 = bf2f(Hs[(size_t)s1 * 64 + lane]);
        float h2 = bf2f(Hs[(size_t)s2 * 64 + lane]);
        float h3 = bf2f(Hs[(size_t)s3 * 64 + lane]);
        m = fmaxf(fmaxf(fmaxf(m, h0), h1), fmaxf(h2, h3));
    }
    for (; e < ee; e++) {
        int s0 = uload(ssrc + e);
        m = fmaxf(m, bf2f(Hs[(size_t)s0 * 64 + lane]));
    }
    return m;
}

// block = 4 waves = 2 nodes x 2 relation-halves; partials combined via LDS.
// flags: 1=first chunk, 2=last chunk, 4=layer1 (relu + bf16 out to x1b)
template <int RC>
__global__ void __launch_bounds__(256) agg_k(
    const unsigned short* __restrict__ H, const int* __restrict__ offs,
    const int* __restrict__ ssrc, const unsigned short* __restrict__ xrootb,
    const float* __restrict__ bias, float* __restrict__ aggbuf,
    unsigned short* __restrict__ x1b, float* __restrict__ outf,
    int r0, int rcnt, int flags) {
    __shared__ float part[2][64];
    int wv = threadIdx.x >> 6;
    int lane = threadIdx.x & 63;
    int nd = wv >> 1;
    int half = wv & 1;
    int d = __builtin_amdgcn_readfirstlane(blockIdx.x * 2 + nd);
    int rc = RC ? RC : rcnt;
    int h = rc >> 1;
    int lo = half ? h : 0;
    int hi = half ? rc : h;
    int base = d * 16 + r0;
    float msum = 0.f;
    if constexpr (RC > 0) {
        int bnd[RC + 1];
#pragma unroll
        for (int j = 0; j <= RC; j++) bnd[j] = uload(offs + base + j);
#pragma unroll
        for (int j = 0; j < RC; j++) {
            if (j < lo || j >= hi) continue;
            int e = bnd[j], ee = bnd[j + 1];
            if (e >= ee) continue;
            msum += seg_max(H + (size_t)j * (NNODE * 64), ssrc, e, ee, lane);
        }
    } else {
        for (int j = lo; j < hi; j++) {
            int e = uload(offs + base + j);
            int ee = uload(offs + base + j + 1);
            if (e >= ee) continue;
            msum += seg_max(H + (size_t)j * (NNODE * 64), ssrc, e, ee, lane);
        }
    }
    if (half) part[nd][lane] = msum;
    __syncthreads();
    if (half) return;
    msum += part[nd][lane];
    size_t o = (size_t)d * 64 + lane;
    if (!(flags & 1)) msum += aggbuf[o];
    if (!(flags & 2)) { aggbuf[o] = msum; return; }
    float v = msum + bf2f(xrootb[o]) + bias[lane];
    if (flags & 4) x1b[o] = f2bf(fmaxf(v, 0.f));
    else outf[o] = v;
}

extern "C" void kernel_launch(void* const* d_in, const int* in_sizes, int n_in,
                              void* d_out, int out_size, void* d_ws, size_t ws_size,
                              hipStream_t stream) {
    const float* x      = (const float*)d_in[0];
    const int*   ei     = (const int*)d_in[1];
    const int*   et     = (const int*)d_in[2];
    const float* w1     = (const float*)d_in[3];
    const float* root1  = (const float*)d_in[4];
    const float* bias1  = (const float*)d_in[5];
    const float* comp2  = (const float*)d_in[6];
    const float* bases2 = (const float*)d_in[7];
    const float* root2  = (const float*)d_in[8];
    const float* bias2  = (const float*)d_in[9];
    const int* srcv = ei;
    const int* dstv = ei + ENUM;
    float* out = (float*)d_out;

    char* w = (char*)d_ws;
    size_t off = 0;
    auto alloc = [&](size_t bytes) -> void* {
        void* p = w + off;
        off += (bytes + 255) & ~(size_t)255;
        return p;
    };
    int*   offs     = (int*)alloc((NBINS2 + 1) * sizeof(int));
    int*   cursor   = (int*)alloc((size_t)NBINS2 * sizeof(int));
    int*   partials = (int*)alloc(1024 * sizeof(int));
    int*   ssrc     = (int*)alloc((size_t)ENUM * sizeof(int));
    unsigned short* xb     = (unsigned short*)alloc((size_t)NNODE * 64 * 2); // also x1b
    unsigned short* xrootb = (unsigned short*)alloc((size_t)NNODE * 64 * 2);
    float*          aggbuf = (float*)alloc((size_t)NNODE * 64 * 4);
    unsigned short* frag1  = (unsigned short*)alloc((size_t)RNUM * 4096 * 2);
    unsigned short* frag2  = (unsigned short*)alloc((size_t)RNUM * 4096 * 2);
    unsigned short* rootf1 = (unsigned short*)alloc(4096 * 2);
    unsigned short* rootf2 = (unsigned short*)alloc(4096 * 2);
    size_t fixed = off;
    if (fixed > ws_size) return;
    size_t slab = ((size_t)NNODE * 64 * 2 + 255) & ~(size_t)255;
    int r_per = (int)((ws_size - fixed) / slab);
    if (r_per < 1) return;
    if (r_per > RNUM) r_per = RNUM;
    unsigned short* H = (unsigned short*)alloc((size_t)r_per * slab);

    hipMemsetAsync(cursor, 0, (size_t)NBINS2 * sizeof(int), stream);

    hist_k<<<(ENUM + 255) / 256, 256, 0, stream>>>(dstv, et, cursor);
    scan_blocks_k<<<NBSC, 256, 0, stream>>>(cursor, offs, partials);
    scan_partials_k<<<1, 1024, 0, stream>>>(partials);
    scan_add_k<<<NBSC, 256, 0, stream>>>(offs, partials);
    hipMemcpyAsync(cursor, offs, (size_t)NBINS2 * sizeof(int), hipMemcpyDeviceToDevice, stream);
    scatter_k<<<(ENUM + 255) / 256, 256, 0, stream>>>(srcv, dstv, et, cursor, ssrc);

    wfrag1_k<<<(RNUM * 4096 + 255) / 256, 256, 0, stream>>>(w1, frag1);
    wfrag2_k<<<(RNUM * 4096 + 255) / 256, 256, 0, stream>>>(comp2, bases2, frag2);
    rootfrag_k<<<16, 256, 0, stream>>>(root1, rootf1);
    rootfrag_k<<<16, 256, 0, stream>>>(root2, rootf2);
    xb_k<<<(NNODE * 64 + 255) / 256, 256, 0, stream>>>(x, xb);

    int nch = (RNUM + r_per - 1) / r_per;
    int aggGrid = NNODE / 2;  // 2 nodes per block

    // ---- layer 1 ----
    gemm_k<<<NTB, 256, 0, stream>>>(xb, rootf1, xrootb);
    for (int c = 0; c < nch; c++) {
        int r0 = c * r_per;
        int rcnt = (RNUM - r0 < r_per) ? (RNUM - r0) : r_per;
        gemm_k<<<rcnt * NTB, 256, 0, stream>>>(xb, frag1 + (size_t)r0 * 4096, H);
        int flags = 4 | (c == 0 ? 1 : 0) | (c == nch - 1 ? 2 : 0);
        if (rcnt == RNUM)
            agg_k<RNUM><<<aggGrid, 256, 0, stream>>>(H, offs, ssrc, xrootb, bias1, aggbuf,
                                                     xb, out, r0, rcnt, flags);
        else
            agg_k<0><<<aggGrid, 256, 0, stream>>>(H, offs, ssrc, xrootb, bias1, aggbuf,
                                                  xb, out, r0, rcnt, flags);
    }

    // ---- layer 2 ----
    gemm_k<<<NTB, 256, 0, stream>>>(xb, rootf2, xrootb);
    for (int c = 0; c < nch; c++) {
        int r0 = c * r_per;
        int rcnt = (RNUM - r0 < r_per) ? (RNUM - r0) : r_per;
        gemm_k<<<rcnt * NTB, 256, 0, stream>>>(xb, frag2 + (size_t)r0 * 4096, H);
        int flags = (c == 0 ? 1 : 0) | (c == nch - 1 ? 2 : 0);
        if (rcnt == RNUM)
            agg_k<RNUM><<<aggGrid, 256, 0, stream>>>(H, offs, ssrc, xrootb, bias2, aggbuf,
                                                     xb, out, r0, rcnt, flags);
        else
            agg_k<0><<<aggGrid, 256, 0, stream>>>(H, offs, ssrc, xrootb, bias2, aggbuf,
                                                  xb, out, r0, rcnt, flags);
    }
}